// Round 12
// baseline (3134.067 us; speedup 1.0000x reference)
//
#include <hip/hip_runtime.h>
#include <math.h>

#define N_    256
#define B_    64
#define S_    256
#define A_    32
#define SA    (S_ * A_)   // 8192
#define NSZ   4           // n-columns per block (64 blocks cover 256 n)
#define CB    8           // batches per chain
#define AROWS 33          // 32 action rows + 1 fused static row (lds idx 32)
#define J0_   (-0.1f)
#define J1_   (0.1f)
#define ALPHA_ 0.15f
#define WIDTH_ 25.6f
#define TWO_PI 6.283185307179586f

// ws floats: r dbuf [8 chain][2 parity][8 b][256 n] = 32768, then flags 8*64
#define RPAR      (CB * N_)               // 2048 floats per parity
#define RCH       (2 * RPAR)              // 4096 per chain
#define FLAG_OFF  (8 * RCH)               // 32768

// LDS floats: weights | r-stage x2 chains | a_t dbuf x2 chains | ctrs
#define WA_LDS_FLOATS (NSZ * AROWS * N_)            // 33792
#define RLDS_OFF   WA_LDS_FLOATS                    // 2 x 2048
#define AT_OFF     (WA_LDS_FLOATS + 2 * RPAR)       // 2 x 2 x 256
#define CTR_OFF_L  (AT_OFF + 1024)                  // 8 uints
#define LDS_BYTES  ((CTR_OFF_L + 8) * 4)            // 155680

// device-coherent (LLC) 16B load — round-3-proven
#define LOADX4_COH(dst, p) \
  asm volatile("global_load_dwordx4 %0, %1, off sc0 sc1" \
               : "=v"(dst) : "v"(p) : "memory")
#define WAIT_VM0() asm volatile("s_waitcnt vmcnt(0)" ::: "memory")
#define WAIT_LGKM0() asm volatile("s_waitcnt lgkmcnt(0)" ::: "memory")
#define FENCE_SCHED() do { asm volatile("" ::: "memory"); \
    __builtin_amdgcn_sched_barrier(0); } while (0)

// lane's 16B of LDS w-row a (immediate offset after unroll)
#define LW(a) (*reinterpret_cast<const float4*>(wrow + (a) * N_ + mq * 4))

#define ACC1(i, atv) \
  acc[i] += (atv) * (w_.x*rr[i][0] + w_.y*rr[i][1] + w_.z*rr[i][2] + w_.w*rr[i][3])

// one a-row: w from LDS, 8 broadcast a_t values of THIS chain ([a][8b] layout)
#define ROWFMA(a) do {                                                        \
    const float4 w_  = LW(a);                                                 \
    const float4 ta_ = *reinterpret_cast<const float4*>(atb + (a)*8);         \
    const float4 tb_ = *reinterpret_cast<const float4*>(atb + (a)*8 + 4);     \
    ACC1(0, ta_.x); ACC1(1, ta_.y); ACC1(2, ta_.z); ACC1(3, ta_.w);           \
    ACC1(4, tb_.x); ACC1(5, tb_.y); ACC1(6, tb_.z); ACC1(7, tb_.w);           \
  } while (0)

__device__ __forceinline__ float bumpval(float idx) {
  float d = fabsf(idx - 128.0f);
  d = fminf(d, 256.0f - d);
  return expf(-d * d / (2.0f * WIDTH_ * WIDTH_));
}

// 256 blocks x 512 threads, cooperative. pair = bid & 3; rank = bid >> 2 owns
// n = 4r..4r+3. Waves 0-3 run chain 2*pair, waves 4-7 run chain 2*pair+1
// (8 batches each, SAME LDS weights). Per-chain 4-wave LDS barriers replace
// __syncthreads in the scan, so when one chain polls its inter-block flags
// (LLC, AGENT scope — r8-proven), the sibling chain's waves own the VALU.
__global__ __launch_bounds__(512, 1)
void ring_scan_kernel(const float* __restrict__ action,  // [64][256][32]
                      const float* __restrict__ Wo,      // [256][256]
                      const float* __restrict__ Wa,      // [32][256][256]
                      float* __restrict__ out,           // r_hist | bump_hist
                      float* __restrict__ rws)
{
  extern __shared__ float lds[];
  float* wa_lds = lds;                                    // [NSZ][AROWS][256]

  const int tid  = threadIdx.x;
  const int bid  = blockIdx.x;
  const int pair = bid & 3;
  const int rank = bid >> 2;                // 0..63
  const int n0   = rank * NSZ;

  // ---- stage LDS: Wa rows 0..31 + fused static row (idx 32) per n ----
  for (int c = tid; c < NSZ * AROWS * (N_ / 4); c += 512) {
    const int rl = c >> 6;            // nl*AROWS + a
    const int q  = c & 63;
    const int nl = rl / AROWS;
    const int a  = rl - nl * AROWS;
    const int n  = n0 + nl;
    float4 v;
    if (a < A_) {
      v = *reinterpret_cast<const float4*>(Wa + ((size_t)a * N_ + n) * N_ + q * 4);
    } else {
      const float4 wo = *reinterpret_cast<const float4*>(Wo + (size_t)n * N_ + q * 4);
      const float* wof = reinterpret_cast<const float*>(&wo);
      float tmp[4];
#pragma unroll
      for (int j = 0; j < 4; ++j) {
        const int m = q * 4 + j;
        tmp[j] = J0_ + J1_ * cosf((float)(n - m) * (TWO_PI / N_)) + wof[j];
      }
      v = make_float4(tmp[0], tmp[1], tmp[2], tmp[3]);
    }
    *reinterpret_cast<float4*>(wa_lds + rl * N_ + q * 4) = v;
  }
  // per-chain barrier counters
  unsigned* ctrs = reinterpret_cast<unsigned*>(lds + CTR_OFF_L);
  if (tid < 8) ctrs[tid] = 0;

  const int wv    = tid >> 6;          // 0..7
  const int mq    = tid & 63;
  const int nloc  = wv & 3;
  const int chl   = wv >> 2;           // chain-local 0/1
  const int chain = pair * 2 + chl;    // 0..7
  const int b0c   = chain * CB;
  const int nG    = n0 + nloc;
  const int l     = nloc * 64 + mq;    // 0..255 within chain
  float*    r_lds = lds + RLDS_OFF + chl * RPAR;        // [8 b][256 n]
  float*    at_c  = lds + AT_OFF + chl * 512;           // [2][32 a][8 b]
  unsigned* ctr1  = ctrs + chl * 2;
  unsigned* ctr2  = ctrs + chl * 2 + 1;
  float*    rbase = rws + chain * RCH;
  unsigned* flags = reinterpret_cast<unsigned*>(rws + FLAG_OFF) + chain * 64;
  const float* wrow = wa_lds + nloc * (AROWS * N_);
  const size_t bump_base = (size_t)B_ * S_ * N_;

  // a_t(0) into parity-0 buffer: chain's 256 lanes, one elem each ([a][8b])
  at_c[(l & 31) * 8 + (l >> 5)] =
      action[(size_t)(b0c + (l >> 5)) * SA + (l & 31)];

  // ---- r0 in registers (analytic, batch-uniform) ----
  float g[4]; float ss = 0.0f;
#pragma unroll
  for (int j = 0; j < 4; ++j) { g[j] = bumpval((float)(mq * 4 + j)); ss += g[j] * g[j]; }
#pragma unroll
  for (int off = 1; off < 64; off <<= 1) ss += __shfl_xor(ss, off, 64);
  const float inv_norm = 1.0f / sqrtf(ss);

  float rr[8][4];
#pragma unroll
  for (int b = 0; b < 8; ++b)
#pragma unroll
    for (int j = 0; j < 4; ++j) rr[b][j] = g[j] * inv_norm;
  float rprev = (mq < 8) ? bumpval((float)nG) * inv_norm : 0.0f;

  __syncthreads();   // weights + a_t(0) + ctrs ready (block-wide, once)

  // ---- main scan (per-chain synchronization only) ----
  for (int t = 0; t < S_; ++t) {
    const float* atb = at_c + (t & 1) * 256;

    float acc[8];
#pragma unroll
    for (int b = 0; b < 8; ++b) acc[b] = 0.0f;

#pragma unroll
    for (int a = 0; a < A_; ++a) ROWFMA(a);
    {   // fused static row (at == 1)
      const float4 w_ = LW(A_);
#pragma unroll
      for (int b = 0; b < 8; ++b)
        acc[b] += w_.x*rr[b][0] + w_.y*rr[b][1] + w_.z*rr[b][2] + w_.w*rr[b][3];
    }

    // ---- split butterfly: lane mq ends with total for b = mq&7 ----
    const int bit0 = mq & 1, bit1 = mq & 2, bit2 = mq & 4;
    float t0 = bit0 ? acc[1] : acc[0], s0 = bit0 ? acc[0] : acc[1];
    float t1 = bit0 ? acc[3] : acc[2], s1 = bit0 ? acc[2] : acc[3];
    float t2 = bit0 ? acc[5] : acc[4], s2 = bit0 ? acc[4] : acc[5];
    float t3 = bit0 ? acc[7] : acc[6], s3 = bit0 ? acc[6] : acc[7];
    const float u0 = t0 + __shfl_xor(s0, 1, 64);
    const float u1 = t1 + __shfl_xor(s1, 1, 64);
    const float u2 = t2 + __shfl_xor(s2, 1, 64);
    const float u3 = t3 + __shfl_xor(s3, 1, 64);
    const float p0 = bit1 ? u1 : u0, q0 = bit1 ? u0 : u1;
    const float p1 = bit1 ? u3 : u2, q1 = bit1 ? u2 : u3;
    const float m0 = p0 + __shfl_xor(q0, 2, 64);
    const float m1 = p1 + __shfl_xor(q1, 2, 64);
    const float f0 = bit2 ? m1 : m0, g0 = bit2 ? m0 : m1;
    float f = f0 + __shfl_xor(g0, 4, 64);
    f += __shfl_xor(f, 8, 64);
    f += __shfl_xor(f, 16, 64);
    f += __shfl_xor(f, 32, 64);

    float rnew = 0.0f;
    if (mq < 8) {
      rnew = (1.0f - ALPHA_) * rprev + ALPHA_ * fmaxf(f, 0.0f);
      rprev = rnew;
      __hip_atomic_store(rbase + (t & 1) * RPAR + mq * N_ + nG, rnew,
                         __ATOMIC_RELAXED, __HIP_MEMORY_SCOPE_AGENT);
      out[bump_base + ((size_t)(b0c + mq) * S_ + t) * N_ + nG] = rnew;
    }
    if (t == S_ - 1) break;

    WAIT_VM0();               // this wave's r store acked at LLC
    // barrier 1 (arrive-only for non-leaders; leader waits then raises flag)
    WAIT_LGKM0();
    if (mq == 0) atomicAdd(ctr1, 1u);
    if (nloc == 0) {
      const unsigned tg = 4u * (unsigned)(t + 1);
      while (*(volatile unsigned*)ctr1 < tg) __builtin_amdgcn_s_sleep(1);
      FENCE_SCHED();
      if (mq == 0)
        __hip_atomic_store(&flags[rank], (unsigned)(t + 1),
                           __ATOMIC_RELAXED, __HIP_MEMORY_SCOPE_AGENT);
    }

    // stage a_t(t+1) into the other parity buffer (overlaps barrier window)
    at_c[((t + 1) & 1) * 256 + (l & 31) * 8 + (l >> 5)] =
        action[(size_t)(b0c + (l >> 5)) * SA + (size_t)(t + 1) * A_ + (l & 31)];

    // poll this chain's 64 inter-block flags (all 4 waves; sibling chain
    // keeps the SIMDs busy while we sleep)
    {
      const unsigned tgt = (unsigned)(t + 1);
      while (true) {
        const unsigned fl = __hip_atomic_load(&flags[mq], __ATOMIC_RELAXED,
                                              __HIP_MEMORY_SCOPE_AGENT);
        if (__all((int)(fl >= tgt))) break;
        __builtin_amdgcn_s_sleep(1);
      }
    }

    // reload r(t): chain's 256 lanes fetch 2048 floats coherently -> LDS
    {
      const float* rsrc = rbase + (t & 1) * RPAR;
      float4 q0, q1;
      LOADX4_COH(q0, rsrc + l * 4);
      LOADX4_COH(q1, rsrc + 1024 + l * 4);
      WAIT_VM0();
      FENCE_SCHED();
      *reinterpret_cast<float4*>(r_lds + l * 4)        = q0;
      *reinterpret_cast<float4*>(r_lds + 1024 + l * 4) = q1;
    }
    // barrier 2 (all 4 waves: staged data visible)
    WAIT_LGKM0();
    if (mq == 0) atomicAdd(ctr2, 1u);
    {
      const unsigned tg = 4u * (unsigned)(t + 1);
      while (*(volatile unsigned*)ctr2 < tg) __builtin_amdgcn_s_sleep(1);
      FENCE_SCHED();
    }
#pragma unroll
    for (int b = 0; b < 8; ++b) {
      const float4 rb = *reinterpret_cast<const float4*>(r_lds + b * N_ + mq * 4);
      rr[b][0] = rb.x; rr[b][1] = rb.y; rr[b][2] = rb.z; rr[b][3] = rb.w;
    }
  }

  // ---- final barrier with device fences (bump visibility for epilogue) ----
  WAIT_VM0();
  __threadfence();
  __syncthreads();
  if (nloc == 0 && mq == 0)          // each chain's leader raises done-flag
    __hip_atomic_store(&flags[rank], 256u, __ATOMIC_RELAXED,
                       __HIP_MEMORY_SCOPE_AGENT);
  if (wv == 0 || wv == 4) {          // one wave per chain polls its 64 flags
    while (true) {
      const unsigned fl = __hip_atomic_load(&flags[mq], __ATOMIC_RELAXED,
                                            __HIP_MEMORY_SCOPE_AGENT);
      if (__all((int)(fl >= 256u))) break;
      __builtin_amdgcn_s_sleep(1);
    }
  }
  __syncthreads();
  __threadfence();

  // ---- epilogue: rank-2 Wd, this pair's 16 batches (both chains) ----
  float cm[4], sm[4];
#pragma unroll
  for (int j = 0; j < 4; ++j) {
    const float ang = (float)(mq * 4 + j) * (TWO_PI / N_);
    cm[j] = cosf(ang);
    sm[j] = sinf(ang);
  }
  const float* bump = out + bump_base;
  for (int it = 0; it < 8; ++it) {
    const int row_local = rank * 64 + it * 8 + wv;      // 0..4095 per pair
    const int b = pair * 16 + (row_local >> 8);
    const int s = row_local & 255;
    const size_t row = (size_t)b * S_ + s;
    const float4 v = *reinterpret_cast<const float4*>(bump + row * N_ + mq * 4);
    float C  = cm[0]*v.x + cm[1]*v.y + cm[2]*v.z + cm[3]*v.w;
    float Sv = sm[0]*v.x + sm[1]*v.y + sm[2]*v.z + sm[3]*v.w;
#pragma unroll
    for (int off = 1; off < 64; off <<= 1) {
      C  += __shfl_xor(C,  off, 64);
      Sv += __shfl_xor(Sv, off, 64);
    }
    float y[4];
#pragma unroll
    for (int j = 0; j < 4; ++j) y[j] = cm[j] * C + sm[j] * Sv;
    float mx = fmaxf(fmaxf(y[0], y[1]), fmaxf(y[2], y[3]));
#pragma unroll
    for (int off = 1; off < 64; off <<= 1) mx = fmaxf(mx, __shfl_xor(mx, off, 64));
    const float inv = 1.0f / mx;
    *reinterpret_cast<float4*>(out + row * N_ + mq * 4) =
        make_float4(y[0] * inv, y[1] * inv, y[2] * inv, y[3] * inv);
  }
}

extern "C" void kernel_launch(void* const* d_in, const int* in_sizes, int n_in,
                              void* d_out, int out_size, void* d_ws, size_t ws_size,
                              hipStream_t stream) {
  const float* action = (const float*)d_in[0];
  const float* Wo     = (const float*)d_in[1];
  const float* Wa     = (const float*)d_in[2];
  float* out = (float*)d_out;
  float* rws = (float*)d_ws;

  // zero the 8x64 chain flags each launch (stream-ordered, capture-safe)
  (void)hipMemsetAsync((char*)d_ws + FLAG_OFF * sizeof(float), 0, 2048, stream);

  (void)hipFuncSetAttribute(reinterpret_cast<const void*>(ring_scan_kernel),
                            hipFuncAttributeMaxDynamicSharedMemorySize, LDS_BYTES);

  void* args[] = {(void*)&action, (void*)&Wo, (void*)&Wa, (void*)&out, (void*)&rws};
  (void)hipLaunchCooperativeKernel(reinterpret_cast<const void*>(ring_scan_kernel),
                                   dim3(256), dim3(512), args,
                                   (unsigned int)LDS_BYTES, stream);
}

// Round 13
// 1430.138 us; speedup vs baseline: 2.1914x; 2.1914x over previous
//
#include <hip/hip_runtime.h>
#include <math.h>

#define N_    256
#define B_    64
#define S_    256
#define A_    32
#define NSZ   8           // n-columns per block (32 blocks x 8n per group)
#define BSZ   8           // batches per group
#define LROWS 18          // LDS rows per n: Wa[0..16] + static row (lds idx 17)
#define ATS   12          // at_lds row stride (floats)
#define AROWS 33
#define J0_   (-0.1f)
#define J1_   (0.1f)
#define ALPHA_ 0.15f
#define WIDTH_ 25.6f
#define TWO_PI 6.283185307179586f

// ws floats: r dbuf [8 grp][2][8 b][256 n] = 32768, then flags 8*32 uint
#define RPAR      (BSZ * N_)              // 2048 floats per parity, [b][n]
#define RGRP      (2 * RPAR)
#define FLAG_OFF  (8 * RGRP)              // 32768

#define WA_LDS_FLOATS (NSZ * LROWS * N_)  // 36864
#define AT_LDS_FLOATS (2 * AROWS * ATS)   // 792
#define RLDS_FLOATS   (RPAR)              // 2048
#define LDS_BYTES ((WA_LDS_FLOATS + AT_LDS_FLOATS + RLDS_FLOATS) * 4) // 158816

#define NN ((size_t)N_ * N_)

typedef float v2f __attribute__((ext_vector_type(2)));

// device-coherent (LLC) 16B load — round-3-proven
#define LOADX4_COH(dst, p) \
  asm volatile("global_load_dwordx4 %0, %1, off sc0 sc1" \
               : "=v"(dst) : "v"(p) : "memory")
// plain cached 16B load (read-only Wa)
#define LOADX4(dst, p) \
  asm volatile("global_load_dwordx4 %0, %1, off" : "=v"(dst) : "v"(p) : "memory")
#define WAIT_VM0() asm volatile("s_waitcnt vmcnt(0)" ::: "memory")

// per-row FMA, PACKED: 4 batch-pairs via v2f -> v_pk_fma_f32 (2 FMA/inst).
// a_t read from LDS as two b128 (adjacent b pairs land in register pairs).
#define ROWFMA(wvec, a_idx) do {                                              \
    const float* atp_ = atb + (a_idx) * ATS;                                  \
    const float4 t0_ = *reinterpret_cast<const float4*>(atp_);                \
    const float4 t1_ = *reinterpret_cast<const float4*>(atp_ + 4);            \
    const v2f at0_ = {t0_.x, t0_.y}, at1_ = {t0_.z, t0_.w};                   \
    const v2f at2_ = {t1_.x, t1_.y}, at3_ = {t1_.z, t1_.w};                   \
    const v2f wx_ = {(wvec).x, (wvec).x}, wy_ = {(wvec).y, (wvec).y};         \
    const v2f wz_ = {(wvec).z, (wvec).z}, ww_ = {(wvec).w, (wvec).w};         \
    const v2f d0_ = wx_*rrp[0][0] + wy_*rrp[0][1] + wz_*rrp[0][2] + ww_*rrp[0][3]; \
    const v2f d1_ = wx_*rrp[1][0] + wy_*rrp[1][1] + wz_*rrp[1][2] + ww_*rrp[1][3]; \
    const v2f d2_ = wx_*rrp[2][0] + wy_*rrp[2][1] + wz_*rrp[2][2] + ww_*rrp[2][3]; \
    const v2f d3_ = wx_*rrp[3][0] + wy_*rrp[3][1] + wz_*rrp[3][2] + ww_*rrp[3][3]; \
    accp[0] += at0_ * d0_;  accp[1] += at1_ * d1_;                            \
    accp[2] += at2_ * d2_;  accp[3] += at3_ * d3_;                            \
  } while (0)

__device__ __forceinline__ float bumpval(float idx) {
  float d = fabsf(idx - 128.0f);
  d = fminf(d, 256.0f - d);
  return expf(-d * d / (2.0f * WIDTH_ * WIDTH_));
}

// 256 blocks x 512 threads, cooperative — r8 structure verbatim, inner loop
// packed. grp = bid & 7 owns batches 8g..8g+7; rank = bid >> 3 owns n=8r..8r+7
// (wave w -> n0+w). 18 weight rows/n in LDS + 15 rows/n in VGPRs. r exchange
// at LLC (AGENT atomics / sc0sc1), staged through LDS once per block per step.
__global__ __launch_bounds__(512, 1)
void ring_scan_kernel(const float* __restrict__ action,  // [64][256][32]
                      const float* __restrict__ Wo,      // [256][256]
                      const float* __restrict__ Wa,      // [32][256][256]
                      float* __restrict__ out,           // r_hist | bump_hist
                      float* __restrict__ rws)
{
  extern __shared__ float lds[];
  float* wa_lds = lds;                                   // [NSZ][LROWS][256]
  float* at_lds = lds + WA_LDS_FLOATS;                   // [2][AROWS][ATS]
  float* r_lds  = lds + WA_LDS_FLOATS + AT_LDS_FLOATS;   // [8 b][256 n]

  const int tid  = threadIdx.x;
  const int bid  = blockIdx.x;
  const int grp  = bid & 7;
  const int rank = bid >> 3;                // 0..31
  const int b0   = grp * BSZ;
  const int n0   = rank * NSZ;
  float*    rbase = rws + grp * RGRP;
  unsigned* flags = reinterpret_cast<unsigned*>(rws + FLAG_OFF) + grp * 32;

  // ---- stage LDS: Wa rows 0..16 + fused static row (idx 17) per n ----
  for (int c = tid; c < NSZ * LROWS * (N_ / 4); c += 512) {
    const int rl = c >> 6;            // nl*LROWS + a
    const int q  = c & 63;
    const int nl = rl / LROWS;
    const int a  = rl - nl * LROWS;
    const int n  = n0 + nl;
    float4 v;
    if (a < 17) {
      v = *reinterpret_cast<const float4*>(Wa + ((size_t)a * N_ + n) * N_ + q * 4);
    } else {
      const float4 wo = *reinterpret_cast<const float4*>(Wo + (size_t)n * N_ + q * 4);
      const float* wof = reinterpret_cast<const float*>(&wo);
      float tmp[4];
#pragma unroll
      for (int j = 0; j < 4; ++j) {
        const int m = q * 4 + j;
        tmp[j] = J0_ + J1_ * cosf((float)(n - m) * (TWO_PI / N_)) + wof[j];
      }
      v = make_float4(tmp[0], tmp[1], tmp[2], tmp[3]);
    }
    *reinterpret_cast<float4*>(wa_lds + rl * N_ + q * 4) = v;
  }
  // a_t virtual row (a=32) = 1.0, both buffers, once
  if (tid < 16)
    at_lds[(tid >> 3) * (AROWS * ATS) + A_ * ATS + (tid & 7)] = 1.0f;
  // a_t(0) into buffer 0
  if (tid < 256) {
    const int b = tid >> 5, a = tid & 31;
    at_lds[a * ATS + b] = action[((size_t)(b0 + b) * S_) * A_ + a];
  }

  const int wv = tid >> 6;
  const int mq = tid & 63;
  const int nG = n0 + wv;
  const float* wrow = wa_lds + wv * (LROWS * N_);
  const size_t bump_base = (size_t)B_ * S_ * N_;

  // ---- pin Wa rows 17..31 for (nG, mq) in 60 VGPRs (loaded ONCE) ----
  float4 sw0,sw1,sw2,sw3,sw4,sw5,sw6,sw7,sw8,sw9,sw10,sw11,sw12,sw13,sw14;
  {
    const float* wg = Wa + ((size_t)17 * N_ + nG) * N_ + mq * 4;
    LOADX4(sw0,  wg);           LOADX4(sw1,  wg + 1*NN);
    LOADX4(sw2,  wg + 2*NN);    LOADX4(sw3,  wg + 3*NN);
    LOADX4(sw4,  wg + 4*NN);    LOADX4(sw5,  wg + 5*NN);
    LOADX4(sw6,  wg + 6*NN);    LOADX4(sw7,  wg + 7*NN);
    LOADX4(sw8,  wg + 8*NN);    LOADX4(sw9,  wg + 9*NN);
    LOADX4(sw10, wg + 10*NN);   LOADX4(sw11, wg + 11*NN);
    LOADX4(sw12, wg + 12*NN);   LOADX4(sw13, wg + 13*NN);
    LOADX4(sw14, wg + 14*NN);
  }

  // ---- r0 in registers (packed batch-pairs) ----
  float g[4]; float ss = 0.0f;
#pragma unroll
  for (int j = 0; j < 4; ++j) { g[j] = bumpval((float)(mq * 4 + j)); ss += g[j] * g[j]; }
#pragma unroll
  for (int off = 1; off < 64; off <<= 1) ss += __shfl_xor(ss, off, 64);
  const float inv_norm = 1.0f / sqrtf(ss);

  v2f rrp[4][4];
#pragma unroll
  for (int p = 0; p < 4; ++p)
#pragma unroll
    for (int j = 0; j < 4; ++j) {
      const float rv = g[j] * inv_norm;
      rrp[p][j] = (v2f){rv, rv};
    }
  float rprev = (mq < 8) ? bumpval((float)nG) * inv_norm : 0.0f;

  __syncthreads();   // LDS ready
  WAIT_VM0();        // sw pinned

  // ---- main scan ----
  for (int t = 0; t < S_; ++t) {
    const float* atb = at_lds + (t & 1) * (AROWS * ATS);

    if (t > 0) {   // r(t): ONE coherent 16B load per thread -> LDS -> regs
      const float* rsrc = rbase + ((t - 1) & 1) * RPAR;
      float4 rq;
      LOADX4_COH(rq, rsrc + tid * 4);
      WAIT_VM0();
      __builtin_amdgcn_sched_barrier(0);
      *reinterpret_cast<float4*>(r_lds + tid * 4) = rq;
      __syncthreads();
#pragma unroll
      for (int p = 0; p < 4; ++p) {
        const float4 ra = *reinterpret_cast<const float4*>(r_lds + (2*p)   * N_ + mq * 4);
        const float4 rb = *reinterpret_cast<const float4*>(r_lds + (2*p+1) * N_ + mq * 4);
        rrp[p][0] = (v2f){ra.x, rb.x};
        rrp[p][1] = (v2f){ra.y, rb.y};
        rrp[p][2] = (v2f){ra.z, rb.z};
        rrp[p][3] = (v2f){ra.w, rb.w};
      }
    }

    v2f accp[4];
#pragma unroll
    for (int p = 0; p < 4; ++p) accp[p] = (v2f){0.0f, 0.0f};

#pragma unroll
    for (int a = 0; a < LROWS; ++a) {       // LDS rows; idx 17 = static (at=1)
      const float4 w = *reinterpret_cast<const float4*>(wrow + a * N_ + mq * 4);
      ROWFMA(w, (a < 17) ? a : 32);
    }
    // register-pinned rows a = 17..31
    ROWFMA(sw0, 17);  ROWFMA(sw1, 18);  ROWFMA(sw2, 19);  ROWFMA(sw3, 20);
    ROWFMA(sw4, 21);  ROWFMA(sw5, 22);  ROWFMA(sw6, 23);  ROWFMA(sw7, 24);
    ROWFMA(sw8, 25);  ROWFMA(sw9, 26);  ROWFMA(sw10, 27); ROWFMA(sw11, 28);
    ROWFMA(sw12, 29); ROWFMA(sw13, 30); ROWFMA(sw14, 31);

    // unpack pairs (register aliasing, ~free)
    float acc[8];
#pragma unroll
    for (int p = 0; p < 4; ++p) { acc[2*p] = accp[p].x; acc[2*p+1] = accp[p].y; }

    // ---- split butterfly: lane mq ends with total for b = mq&7 ----
    const int bit0 = mq & 1, bit1 = mq & 2, bit2 = mq & 4;
    float t0 = bit0 ? acc[1] : acc[0], s0 = bit0 ? acc[0] : acc[1];
    float t1 = bit0 ? acc[3] : acc[2], s1 = bit0 ? acc[2] : acc[3];
    float t2 = bit0 ? acc[5] : acc[4], s2 = bit0 ? acc[4] : acc[5];
    float t3 = bit0 ? acc[7] : acc[6], s3 = bit0 ? acc[6] : acc[7];
    const float u0 = t0 + __shfl_xor(s0, 1, 64);
    const float u1 = t1 + __shfl_xor(s1, 1, 64);
    const float u2 = t2 + __shfl_xor(s2, 1, 64);
    const float u3 = t3 + __shfl_xor(s3, 1, 64);
    const float p0 = bit1 ? u1 : u0, q0 = bit1 ? u0 : u1;
    const float p1 = bit1 ? u3 : u2, q1 = bit1 ? u2 : u3;
    const float m0 = p0 + __shfl_xor(q0, 2, 64);
    const float m1 = p1 + __shfl_xor(q1, 2, 64);
    const float f0 = bit2 ? m1 : m0, g0 = bit2 ? m0 : m1;
    float f = f0 + __shfl_xor(g0, 4, 64);
    f += __shfl_xor(f, 8, 64);
    f += __shfl_xor(f, 16, 64);
    f += __shfl_xor(f, 32, 64);

    float rnew = 0.0f;
    if (mq < 8) {
      rnew = (1.0f - ALPHA_) * rprev + ALPHA_ * fmaxf(f, 0.0f);
      rprev = rnew;
      __hip_atomic_store(rbase + (t & 1) * RPAR + mq * N_ + nG, rnew,
                         __ATOMIC_RELAXED, __HIP_MEMORY_SCOPE_AGENT);
    }

    if (t == S_ - 1) {
      if (mq < 8)
        out[bump_base + ((size_t)(b0 + mq) * S_ + t) * N_ + nG] = rnew;
      break;
    }

    WAIT_VM0();           // r stores acked at LLC (per wave)
    __syncthreads();      // all waves drained
    if (tid == 0)
      __hip_atomic_store(&flags[rank], (unsigned)(t + 1),
                         __ATOMIC_RELAXED, __HIP_MEMORY_SCOPE_AGENT);

    // bump store + next a_t staging overlap the barrier window
    if (mq < 8)
      out[bump_base + ((size_t)(b0 + mq) * S_ + t) * N_ + nG] = rnew;
    if (tid < 256) {
      const int b = tid >> 5, a = tid & 31;
      at_lds[((t + 1) & 1) * (AROWS * ATS) + a * ATS + b] =
          action[((size_t)(b0 + b) * S_ + (t + 1)) * A_ + a];
    }

    if (wv == 0) {        // wave 0 polls the 32 group flags (lanes 0-31 live)
      const unsigned tgt = (unsigned)(t + 1);
      while (true) {
        const unsigned fl = __hip_atomic_load(&flags[mq & 31], __ATOMIC_RELAXED,
                                              __HIP_MEMORY_SCOPE_AGENT);
        if (__all((int)(fl >= tgt))) break;
        __builtin_amdgcn_s_sleep(1);
      }
    }
    __syncthreads();
  }

  // ---- final barrier with device fences (bump visibility for epilogue) ----
  __threadfence();
  __syncthreads();
  if (tid == 0)
    __hip_atomic_store(&flags[rank], 256u, __ATOMIC_RELAXED,
                       __HIP_MEMORY_SCOPE_AGENT);
  if (wv == 0) {
    while (true) {
      const unsigned fl = __hip_atomic_load(&flags[mq & 31], __ATOMIC_RELAXED,
                                            __HIP_MEMORY_SCOPE_AGENT);
      if (__all((int)(fl >= 256u))) break;
      __builtin_amdgcn_s_sleep(1);
    }
  }
  __syncthreads();
  __threadfence();

  // ---- epilogue: rank-2 Wd, this group's rows only ----
  float cm[4], sm[4];
#pragma unroll
  for (int j = 0; j < 4; ++j) {
    const float ang = (float)(mq * 4 + j) * (TWO_PI / N_);
    cm[j] = cosf(ang);
    sm[j] = sinf(ang);
  }
  const float* bump = out + bump_base;
  for (int it = 0; it < 8; ++it) {
    const int row_local = rank * 64 + it * 8 + wv;      // 0..2047 per group
    const int b = b0 + (row_local >> 8);
    const int s = row_local & 255;
    const size_t row = (size_t)b * S_ + s;
    const float4 v = *reinterpret_cast<const float4*>(bump + row * N_ + mq * 4);
    float C  = cm[0]*v.x + cm[1]*v.y + cm[2]*v.z + cm[3]*v.w;
    float Sv = sm[0]*v.x + sm[1]*v.y + sm[2]*v.z + sm[3]*v.w;
#pragma unroll
    for (int off = 1; off < 64; off <<= 1) {
      C  += __shfl_xor(C,  off, 64);
      Sv += __shfl_xor(Sv, off, 64);
    }
    float y[4];
#pragma unroll
    for (int j = 0; j < 4; ++j) y[j] = cm[j] * C + sm[j] * Sv;
    float mx = fmaxf(fmaxf(y[0], y[1]), fmaxf(y[2], y[3]));
#pragma unroll
    for (int off = 1; off < 64; off <<= 1) mx = fmaxf(mx, __shfl_xor(mx, off, 64));
    const float inv = 1.0f / mx;
    *reinterpret_cast<float4*>(out + row * N_ + mq * 4) =
        make_float4(y[0] * inv, y[1] * inv, y[2] * inv, y[3] * inv);
  }
}

extern "C" void kernel_launch(void* const* d_in, const int* in_sizes, int n_in,
                              void* d_out, int out_size, void* d_ws, size_t ws_size,
                              hipStream_t stream) {
  const float* action = (const float*)d_in[0];
  const float* Wo     = (const float*)d_in[1];
  const float* Wa     = (const float*)d_in[2];
  float* out = (float*)d_out;
  float* rws = (float*)d_ws;

  // zero the barrier flags each launch (stream-ordered, capture-safe)
  (void)hipMemsetAsync((char*)d_ws + FLAG_OFF * sizeof(float), 0, 1024, stream);

  (void)hipFuncSetAttribute(reinterpret_cast<const void*>(ring_scan_kernel),
                            hipFuncAttributeMaxDynamicSharedMemorySize, LDS_BYTES);

  void* args[] = {(void*)&action, (void*)&Wo, (void*)&Wa, (void*)&out, (void*)&rws};
  (void)hipLaunchCooperativeKernel(reinterpret_cast<const void*>(ring_scan_kernel),
                                   dim3(256), dim3(512), args,
                                   (unsigned int)LDS_BYTES, stream);
}